// Round 13
// baseline (203.457 us; speedup 1.0000x reference)
//
#include <hip/hip_runtime.h>
#include <math.h>

namespace {

typedef _Float16 f16_t;
typedef __attribute__((ext_vector_type(8))) _Float16 f16x8;
typedef __attribute__((ext_vector_type(4))) float f32x4;

constexpr int kN = 4096;   // tokens
constexpr int kC = 1024;   // channels
constexpr int kH = 16;     // heads
constexpr int kD = 64;     // head dim
constexpr int kL = 512;    // window length (8^3)

__device__ __forceinline__ void gload16(const void* g, void* l) {
  __builtin_amdgcn_global_load_lds(
      (const __attribute__((address_space(1))) unsigned int*)g,
      (__attribute__((address_space(3))) unsigned int*)l, 16, 0, 0);
}

// ---------------------------------------------------------------------------
// fp32 [M][K] row-major -> fp16 [(K/8)][M][8] (k-major packed).
// ---------------------------------------------------------------------------
__global__ __launch_bounds__(256) void pack_rows_f16(
    const float* __restrict__ src, f16_t* __restrict__ dst, int M, int K) {
  __shared__ __align__(16) f16_t Th[64][72];
  const int t = threadIdx.x;
  const int m0 = blockIdx.x * 64, k0 = blockIdx.y * 64;
#pragma unroll
  for (int it = 0; it < 4; ++it) {
    const int slot = it * 256 + t;  // 0..1023
    const int m = slot >> 4;
    const int k4 = (slot & 15) * 4;
    const float4 v = *(const float4*)&src[(size_t)(m0 + m) * K + k0 + k4];
    Th[m][k4 + 0] = (f16_t)v.x;
    Th[m][k4 + 1] = (f16_t)v.y;
    Th[m][k4 + 2] = (f16_t)v.z;
    Th[m][k4 + 3] = (f16_t)v.w;
  }
  __syncthreads();
#pragma unroll
  for (int it = 0; it < 2; ++it) {
    const int slot = it * 256 + t;  // 0..511
    const int kcl = slot >> 6;      // 0..7
    const int m = slot & 63;
    const size_t o = ((size_t)(blockIdx.y * 8 + kcl) * M + m0 + m) * 8;
    *(f16x8*)&dst[o] = *(const f16x8*)&Th[m][kcl * 8];
  }
}

// ---------------------------------------------------------------------------
// fp32 [K][N] (k-major already) -> fp16 [(K/8)][N][8]. grid (N/256, K/8).
// ---------------------------------------------------------------------------
__global__ __launch_bounds__(256) void pack_w_f16(
    const float* __restrict__ src, f16_t* __restrict__ dst, int K, int N) {
  const int n = blockIdx.x * 256 + threadIdx.x;
  const int kcg = blockIdx.y;
  f16x8 h;
#pragma unroll
  for (int j = 0; j < 8; ++j)
    h[j] = (f16_t)src[(size_t)(kcg * 8 + j) * N + n];
  *(f16x8*)&dst[((size_t)kcg * N + n) * 8] = h;
}

// ---------------------------------------------------------------------------
// Generic single-pass fp16 MFMA GEMM with fp32 out + bias (out-projection).
// Verified r10. 128x128 tile, BK=32, 4 waves (2x2), 4x4 frags 16x16x32.
// ---------------------------------------------------------------------------
__global__ __launch_bounds__(256) void gemm_f16(
    const f16_t* __restrict__ A, const f16_t* __restrict__ B,
    const float* __restrict__ bias, float* __restrict__ C, int M, int N,
    int K) {
  __shared__ __align__(16) f16_t As[4][128][8];  // [kc][m][8]
  __shared__ __align__(16) f16_t Bs[4][128][8];  // [kc][n][8]

  const int t = threadIdx.x;
  const int lane = t & 63;
  const int wid = t >> 6;
  const int wr = wid >> 1, wc = wid & 1;
  const int l15 = lane & 15, lk = lane >> 4;
  const int row0 = blockIdx.y * 128, col0 = blockIdx.x * 128;

  f32x4 acc[4][4];
#pragma unroll
  for (int i = 0; i < 4; ++i)
#pragma unroll
    for (int j = 0; j < 4; ++j) acc[i][j] = (f32x4){0.f, 0.f, 0.f, 0.f};

  for (int k0 = 0; k0 < K; k0 += 32) {
    const int kq = k0 >> 3;
#pragma unroll
    for (int s = 0; s < 2; ++s) {
      const int li = s * 256 + t;  // 0..511
      const int kc = li >> 7;
      const int r = li & 127;
      const size_t goff = (size_t)(kq + kc);
      char* adst = (char*)(&As[0][0][0]) + (size_t)(s * 256 + wid * 64) * 16;
      char* bdst = (char*)(&Bs[0][0][0]) + (size_t)(s * 256 + wid * 64) * 16;
      gload16(&A[(goff * M + row0 + r) * 8], adst);
      gload16(&B[(goff * N + col0 + r) * 8], bdst);
    }
    __syncthreads();

    f16x8 af[4], bf[4];
#pragma unroll
    for (int f = 0; f < 4; ++f) {
      af[f] = *(const f16x8*)&As[lk][wr * 64 + f * 16 + l15][0];
      bf[f] = *(const f16x8*)&Bs[lk][wc * 64 + f * 16 + l15][0];
    }
#pragma unroll
    for (int mf = 0; mf < 4; ++mf)
#pragma unroll
      for (int nf = 0; nf < 4; ++nf)
        acc[mf][nf] = __builtin_amdgcn_mfma_f32_16x16x32_f16(
            af[mf], bf[nf], acc[mf][nf], 0, 0, 0);
    __syncthreads();
  }

#pragma unroll
  for (int mf = 0; mf < 4; ++mf)
#pragma unroll
    for (int nf = 0; nf < 4; ++nf) {
      const int col = col0 + wc * 64 + nf * 16 + l15;
      const float bv = bias[col];
#pragma unroll
      for (int r = 0; r < 4; ++r) {
        const int row = row0 + wr * 64 + mf * 16 + lk * 4 + r;
        C[(size_t)row * N + col] = acc[mf][nf][r] + bv;
      }
    }
}

// ---------------------------------------------------------------------------
// QKV GEMM with FUSED epilogue: bias + per-head RMS-norm + RoPE + window
// permute + fp16 pack, written directly in the attention layouts.
// r12: RoPE trig via LDS lookup table (176 entries: c in [0,16) x fi in
// [0,10]), replacing 64 per-thread __sincosf (epilogue was VALU-bound:
// r11 counters MfmaUtil 19% / VALUBusy 45%).
// ---------------------------------------------------------------------------
__global__ __launch_bounds__(256) void gemm_qkv(
    const f16_t* __restrict__ A, const f16_t* __restrict__ B,
    const float* __restrict__ bias, const int* __restrict__ coords,
    const float* __restrict__ qg, const float* __restrict__ kg,
    f16_t* __restrict__ qwF, f16_t* __restrict__ kwF,
    f16_t* __restrict__ vwF) {
  constexpr int M = kN, N = 3 * kC, K = kC;
  __shared__ __align__(16) f16_t As[4][128][8];
  __shared__ __align__(16) f16_t Bs[4][128][8];
  __shared__ float2 trig[176];  // [c][fi]: (cos,sin) of c*freq[fi]; fi=10 id

  const int t = threadIdx.x;
  const int lane = t & 63;
  const int wid = t >> 6;
  const int wr = wid >> 1, wc = wid & 1;
  const int l15 = lane & 15, lk = lane >> 4;
  const int row0 = blockIdx.y * 128, col0 = blockIdx.x * 128;

  // build trig table (full-precision sincosf, once per block)
  if (t < 176) {
    const int c = t / 11, fi = t - (t / 11) * 11;
    const float ang =
        (fi < 10) ? (float)c * expf(-(float)fi * 0.92103403719761836f) : 0.f;
    float sn, cs;
    sincosf(ang, &sn, &cs);
    trig[t] = make_float2(cs, sn);
  }
  // (ordered before epilogue reads by the K-loop barriers)

  f32x4 acc[4][4];
#pragma unroll
  for (int i = 0; i < 4; ++i)
#pragma unroll
    for (int j = 0; j < 4; ++j) acc[i][j] = (f32x4){0.f, 0.f, 0.f, 0.f};

  for (int k0 = 0; k0 < K; k0 += 32) {
    const int kq = k0 >> 3;
#pragma unroll
    for (int s = 0; s < 2; ++s) {
      const int li = s * 256 + t;
      const int kc = li >> 7;
      const int r = li & 127;
      const size_t goff = (size_t)(kq + kc);
      char* adst = (char*)(&As[0][0][0]) + (size_t)(s * 256 + wid * 64) * 16;
      char* bdst = (char*)(&Bs[0][0][0]) + (size_t)(s * 256 + wid * 64) * 16;
      gload16(&A[(goff * M + row0 + r) * 8], adst);
      gload16(&B[(goff * N + col0 + r) * 8], bdst);
    }
    __syncthreads();

    f16x8 af[4], bf[4];
#pragma unroll
    for (int f = 0; f < 4; ++f) {
      af[f] = *(const f16x8*)&As[lk][wr * 64 + f * 16 + l15][0];
      bf[f] = *(const f16x8*)&Bs[lk][wc * 64 + f * 16 + l15][0];
    }
#pragma unroll
    for (int mf = 0; mf < 4; ++mf)
#pragma unroll
      for (int nf = 0; nf < 4; ++nf)
        acc[mf][nf] = __builtin_amdgcn_mfma_f32_16x16x32_f16(
            af[mf], bf[nf], acc[mf][nf], 0, 0, 0);
    __syncthreads();
  }

  // ---- fused epilogue ----
  const int cb = col0 + wc * 64;      // wave's global col base (0..3008)
  const int tsel = cb >> 10;          // 0=q 1=k 2=v (wave-uniform)
  const int h = (cb >> 6) & 15;       // head (wave-uniform)
  f16_t* obase = (tsel == 0 ? qwF : (tsel == 1 ? kwF : vwF));

  float bv[4], gv[4];
  int axis[4], fi[4];
#pragma unroll
  for (int nf = 0; nf < 4; ++nf) {
    bv[nf] = bias[cb + nf * 16 + l15];
    gv[nf] = (tsel == 0) ? qg[h * kD + nf * 16 + l15]
             : (tsel == 1) ? kg[h * kD + nf * 16 + l15] : 1.f;
    const int j = nf * 8 + (l15 >> 1);  // rope pair index 0..31
    axis[nf] = (j >= 10) + (j >= 20);
    fi[nf] = (j < 30) ? (j - axis[nf] * 10) : 10;  // 10 = identity slot
  }
  const float sgn = (l15 & 1) ? 1.f : -1.f;  // rope: -sin (re) / +sin (im)

#pragma unroll
  for (int mf = 0; mf < 4; ++mf)
#pragma unroll
    for (int r = 0; r < 4; ++r) {
      const int row = row0 + wr * 64 + mf * 16 + lk * 4 + r;
      const int4 cc = *(const int4*)&coords[row * 4];  // (0,z,y,x)
      const int w = ((cc.y >> 3) * 2 + (cc.z >> 3)) * 2 + (cc.w >> 3);
      const int p = ((cc.y & 7) * 8 + (cc.z & 7)) * 8 + (cc.w & 7);
      f16_t* ob = obase + (size_t)(w * kH + h) * 32768;

      float v[4];
#pragma unroll
      for (int nf = 0; nf < 4; ++nf) v[nf] = acc[mf][nf][r] + bv[nf];

      if (tsel < 2) {
        // RMS norm over the 64-col head (reduce across nf + 16-lane group)
        float s = v[0] * v[0] + v[1] * v[1] + v[2] * v[2] + v[3] * v[3];
        s += __shfl_xor(s, 1);
        s += __shfl_xor(s, 2);
        s += __shfl_xor(s, 4);
        s += __shfl_xor(s, 8);
        const float sc = 8.0f / fmaxf(sqrtf(s), 1e-12f);  // sqrt(D)=8
#pragma unroll
        for (int nf = 0; nf < 4; ++nf) v[nf] *= sc * gv[nf];
        // RoPE via LDS table (partner col differs in lane bit0)
#pragma unroll
        for (int nf = 0; nf < 4; ++nf) {
          const int c =
              (axis[nf] == 0 ? cc.y : (axis[nf] == 1 ? cc.z : cc.w));
          const float2 tt = trig[c * 11 + fi[nf]];
          const float partner = __shfl_xor(v[nf], 1);
          v[nf] = v[nf] * tt.x + sgn * tt.y * partner;
        }
        const float qsc = (tsel == 0) ? 0.125f : 1.f;  // fold 1/sqrt(D)
#pragma unroll
        for (int nf = 0; nf < 4; ++nf) {
          const int d = nf * 16 + l15;
          ob[((d >> 3) * kL + p) * 8 + (d & 7)] = (f16_t)(v[nf] * qsc);
        }
      } else {
#pragma unroll
        for (int nf = 0; nf < 4; ++nf) {
          const int d = nf * 16 + l15;
          ob[((p >> 3) * kD + d) * 8 + (p & 7)] = (f16_t)v[nf];
        }
      }
    }
}

// ---------------------------------------------------------------------------
// Windowed attention via fp16 MFMA (f32 accum, online softmax). Verified r10.
// ---------------------------------------------------------------------------
__global__ __launch_bounds__(256) void attn_mfma(
    const f16_t* __restrict__ qw, const f16_t* __restrict__ kw,
    const f16_t* __restrict__ vw, f16_t* __restrict__ ob) {
  __shared__ __align__(16) f16_t Ks[8 * 64 * 8];  // [kq][c][8]
  __shared__ __align__(16) f16_t Vs[8 * 64 * 8];  // [ck][d][8]
  __shared__ __align__(16) f16_t Ps[4][32][72];   // per-wave P buffer

  const int bid = blockIdx.x;
  const int qt = bid & 3;
  const int h = (bid >> 2) & 15;
  const int w = bid >> 6;
  const int t = threadIdx.x;
  const int lane = t & 63;
  const int wid = t >> 6;
  const int l15 = lane & 15, lk = lane >> 4;
  const int whq = w * kH + h;
  const f16_t* qbase = qw + (size_t)whq * 32768;
  const f16_t* kbase = kw + (size_t)whq * 32768;
  const f16_t* vbase = vw + (size_t)whq * 32768;

  const int qrow0 = qt * 128 + wid * 32;

  f16x8 aq[2][2];
#pragma unroll
  for (int m = 0; m < 2; ++m)
#pragma unroll
    for (int ks = 0; ks < 2; ++ks)
      aq[m][ks] = *(const f16x8*)&qbase[((ks * 4 + lk) * kL + qrow0 +
                                         m * 16 + l15) * 8];

  f32x4 oacc[2][4];
  float mrun[2][4], lrun[2][4];
#pragma unroll
  for (int m = 0; m < 2; ++m)
#pragma unroll
    for (int i = 0; i < 4; ++i) {
      mrun[m][i] = -1e30f;
      lrun[m][i] = 0.f;
    }
#pragma unroll
  for (int m = 0; m < 2; ++m)
#pragma unroll
    for (int nf = 0; nf < 4; ++nf) oacc[m][nf] = (f32x4){0.f, 0.f, 0.f, 0.f};

  for (int kt = 0; kt < 8; ++kt) {
    __syncthreads();
#pragma unroll
    for (int s = 0; s < 2; ++s) {
      const int idx = s * 256 + t;
      const int bidx = s * 256 + wid * 64;
      gload16(&kbase[((idx >> 6) * kL + kt * 64 + (idx & 63)) * 8],
              (char*)Ks + (size_t)bidx * 16);
      gload16(&vbase[((kt * 8 + (idx >> 6)) * 64 + (idx & 63)) * 8],
              (char*)Vs + (size_t)bidx * 16);
    }
    __syncthreads();

    f32x4 sacc[2][4];
#pragma unroll
    for (int m = 0; m < 2; ++m)
#pragma unroll
      for (int nf = 0; nf < 4; ++nf) sacc[m][nf] = (f32x4){0.f, 0.f, 0.f, 0.f};
#pragma unroll
    for (int ks = 0; ks < 2; ++ks) {
      f16x8 bk[4];
#pragma unroll
      for (int nf = 0; nf < 4; ++nf)
        bk[nf] = *(const f16x8*)&Ks[((ks * 4 + lk) * 64 + nf * 16 + l15) * 8];
#pragma unroll
      for (int m = 0; m < 2; ++m)
#pragma unroll
        for (int nf = 0; nf < 4; ++nf)
          sacc[m][nf] = __builtin_amdgcn_mfma_f32_16x16x32_f16(
              aq[m][ks], bk[nf], sacc[m][nf], 0, 0, 0);
    }

#pragma unroll
    for (int m = 0; m < 2; ++m)
#pragma unroll
      for (int i = 0; i < 4; ++i) {
        float rmax = fmaxf(fmaxf(sacc[m][0][i], sacc[m][1][i]),
                           fmaxf(sacc[m][2][i], sacc[m][3][i]));
        rmax = fmaxf(rmax, __shfl_xor(rmax, 1));
        rmax = fmaxf(rmax, __shfl_xor(rmax, 2));
        rmax = fmaxf(rmax, __shfl_xor(rmax, 4));
        rmax = fmaxf(rmax, __shfl_xor(rmax, 8));
        const float mn = fmaxf(mrun[m][i], rmax);
        const float corr = __expf(mrun[m][i] - mn);
        mrun[m][i] = mn;
        float p[4];
        float rs = 0.f;
#pragma unroll
        for (int nf = 0; nf < 4; ++nf) {
          p[nf] = __expf(sacc[m][nf][i] - mn);
          rs += p[nf];
        }
        rs += __shfl_xor(rs, 1);
        rs += __shfl_xor(rs, 2);
        rs += __shfl_xor(rs, 4);
        rs += __shfl_xor(rs, 8);
        lrun[m][i] = lrun[m][i] * corr + rs;
#pragma unroll
        for (int nf = 0; nf < 4; ++nf) oacc[m][nf][i] *= corr;
        const int row = m * 16 + lk * 4 + i;
#pragma unroll
        for (int nf = 0; nf < 4; ++nf)
          Ps[wid][row][nf * 16 + l15] = (f16_t)p[nf];
      }

#pragma unroll
    for (int ks = 0; ks < 2; ++ks) {
      f16x8 pa[2], bvv[4];
#pragma unroll
      for (int m = 0; m < 2; ++m)
        pa[m] = *(const f16x8*)&Ps[wid][m * 16 + l15][ks * 32 + lk * 8];
#pragma unroll
      for (int nf = 0; nf < 4; ++nf)
        bvv[nf] = *(const f16x8*)&Vs[((ks * 4 + lk) * 64 + nf * 16 + l15) * 8];
#pragma unroll
      for (int m = 0; m < 2; ++m)
#pragma unroll
        for (int nf = 0; nf < 4; ++nf)
          oacc[m][nf] = __builtin_amdgcn_mfma_f32_16x16x32_f16(
              pa[m], bvv[nf], oacc[m][nf], 0, 0, 0);
    }
  }

  const int wz = w >> 2, wy = (w >> 1) & 1, wx = w & 1;
#pragma unroll
  for (int m = 0; m < 2; ++m)
#pragma unroll
    for (int i = 0; i < 4; ++i) {
      const int pg = qrow0 + m * 16 + lk * 4 + i;
      const int pz = pg >> 6, py = (pg >> 3) & 7, px = pg & 7;
      const int n = ((wz * 8 + pz) * 16 + wy * 8 + py) * 16 + wx * 8 + px;
      const float inv = 1.0f / lrun[m][i];
#pragma unroll
      for (int nf = 0; nf < 4; ++nf) {
        const int c0 = h * kD + nf * 16 + l15;
        ob[((size_t)(c0 >> 3) * kN + n) * 8 + (c0 & 7)] =
            (f16_t)(oacc[m][nf][i] * inv);
      }
    }
}

}  // namespace

extern "C" void kernel_launch(void* const* d_in, const int* in_sizes, int n_in,
                              void* d_out, int out_size, void* d_ws,
                              size_t ws_size, hipStream_t stream) {
  const float* x = (const float*)d_in[0];
  const int* coords = (const int*)d_in[1];
  const float* w_qkv = (const float*)d_in[2];
  const float* b_qkv = (const float*)d_in[3];
  const float* qg = (const float*)d_in[4];
  const float* kg = (const float*)d_in[5];
  const float* w_out = (const float*)d_in[6];
  const float* b_out = (const float*)d_in[7];
  float* out = (float*)d_out;

  char* ws8 = (char*)d_ws;
  f16_t* AF = (f16_t*)ws8;                         // 8 MB
  f16_t* BqF = (f16_t*)(ws8 + 8388608);            // 6 MB
  f16_t* BoF = (f16_t*)(ws8 + 16777216);           // 2 MB
  f16_t* qwF = (f16_t*)(ws8 + 33554432);           // 8 MB
  f16_t* kwF = (f16_t*)(ws8 + 41943040);           // 8 MB
  f16_t* vwF = (f16_t*)(ws8 + 50331648);           // 8 MB
  f16_t* obF = (f16_t*)(ws8 + 58720256);           // 8 MB

  // 1) pack inputs to fp16 (k-major); all three are independent
  pack_rows_f16<<<dim3(kN / 64, kC / 64), 256, 0, stream>>>(x, AF, kN, kC);
  pack_w_f16<<<dim3(3 * kC / 256, kC / 8), 256, 0, stream>>>(w_qkv, BqF, kC,
                                                             3 * kC);
  pack_w_f16<<<dim3(kC / 256, kC / 8), 256, 0, stream>>>(w_out, BoF, kC, kC);
  // 2) QKV projection with fused bias+norm+RoPE+permute epilogue
  gemm_qkv<<<dim3(3 * kC / 128, kN / 128), 256, 0, stream>>>(
      AF, BqF, b_qkv, coords, qg, kg, qwF, kwF, vwF);
  // 3) windowed attention (fp16 MFMA), writes fp16 packed O
  attn_mfma<<<dim3(4 * kH * 8), 256, 0, stream>>>(qwF, kwF, vwF, obF);
  // 4) output projection (fp16 MFMA, fp32 out + bias)
  gemm_f16<<<dim3(kC / 128, kN / 128), 256, 0, stream>>>(
      obF, BoF, b_out, out, kN, kC, kC);
}